// Round 15
// baseline (3272.306 us; speedup 1.0000x reference)
//
#include <hip/hip_runtime.h>

#define TLEN 2048
#define BATCH 32
#define DIN 64
#define HID 128
#define CHK 8          // pipeline chunk (steps)
#define GB 16          // batches per group (2 groups)
#define HPAD 136       // h row pad, halfwords (272 B)
#define XPAD 72        // x row pad, halfwords (144 B)

typedef _Float16 f16;
typedef _Float16 h2 __attribute__((ext_vector_type(2)));
typedef _Float16 h8 __attribute__((ext_vector_type(8)));   // MFMA A/B fragment
typedef float f32x4 __attribute__((ext_vector_type(4)));   // MFMA C/D fragment
typedef float f4 __attribute__((ext_vector_type(4)));
typedef unsigned int u32;

#if defined(__has_builtin)
#if __has_builtin(__builtin_amdgcn_fdot2)
#define FDOT2(a, b, c) __builtin_amdgcn_fdot2((a), (b), (c), false)
#endif
#endif
#ifndef FDOT2
#define FDOT2(a, b, c) ((c) + (float)(a).x * (float)(b).x + (float)(a).y * (float)(b).y)
#endif

// ---- fast activations (R12/R14-proven: absmax unchanged at 9.77e-4) ----
#if defined(__has_builtin)
#if __has_builtin(__builtin_amdgcn_exp2f)
#define FEXP2(x) __builtin_amdgcn_exp2f(x)
#endif
#if __has_builtin(__builtin_amdgcn_rcpf)
#define FRCP(x) __builtin_amdgcn_rcpf(x)
#endif
#endif
#ifndef FEXP2
#define FEXP2(x) __expf((x) * 0.69314718f)
#endif
#ifndef FRCP
#define FRCP(x) (1.0f / (x))
#endif

__device__ __forceinline__ float sigm(float x) {
    return FRCP(1.0f + FEXP2(-1.44269504f * x));
}
__device__ __forceinline__ float tanh_c(float x) {
    x = fminf(fmaxf(x, -15.0f), 15.0f);
    float e = FEXP2(2.88539008f * x);
    return (e - 1.0f) * FRCP(e + 1.0f);
}

// agent-scope atomics (R8/R9/R11-proven cross-XCD path)
__device__ __forceinline__ u32 aload_rlx(const u32* p) {
    return __hip_atomic_load(p, __ATOMIC_RELAXED, __HIP_MEMORY_SCOPE_AGENT);
}
__device__ __forceinline__ u32 aload_acq(const u32* p) {
    return __hip_atomic_load(p, __ATOMIC_ACQUIRE, __HIP_MEMORY_SCOPE_AGENT);
}
__device__ __forceinline__ void astore_rlx(u32* p, u32 v) {
    __hip_atomic_store(p, v, __ATOMIC_RELAXED, __HIP_MEMORY_SCOPE_AGENT);
}
__device__ __forceinline__ void astore_rel(u32* p, u32 v) {
    __hip_atomic_store(p, v, __ATOMIC_RELEASE, __HIP_MEMORY_SCOPE_AGENT);
}

// ============================================================================
// Kernel 1: XT[t][b][c] = (f16) X[b][t][c]  (time-major, f16, for B-staging)
// ============================================================================
__global__ __launch_bounds__(256) void xt_precompute(
    const float* __restrict__ X, f16* __restrict__ XT)
{
    const int t = blockIdx.x;
    for (int idx = threadIdx.x; idx < BATCH * DIN; idx += 256) {
        const int b = idx / DIN, c = idx % DIN;
        XT[(size_t)t * BATCH * DIN + idx] =
            (f16)X[((size_t)b * TLEN + t) * DIN + c];
    }
}

// ============================================================================
// Kernel 2: MFMA 2-stage pipeline (R11-proven structure + fast activations).
// grid = 4: layer = bid>>1, grp = bid&1.
// Per step: gates[512 x GB] = W[512 x K] @ h^T[K x GB] via mfma_16x16x32_f16.
//   A (weights, static) -> AGPR fragments ("+a" pins: PROVEN resident in R11,
//     FETCH=13MB, no reload traffic) - the one register file that works.
//   B (h / x)           -> LDS, padded rows, b128 reads.
//   D lane layout (HW-verified m89): col = lane&15 (batch),
//     row = (lane>>4)*4 + reg.  Wave w takes M-tiles {w,w+8,w+16,w+24}.
// layer0: K = 192 (Whh0 | Wih0), publishes h0 -> H0g + flag per CHK.
// layer1: K = 256 (Wih1 | Whh1), consumes h0 chunks, writes Out.
// ============================================================================
__global__ __launch_bounds__(512, 1) void lstm2_mfma(
    const f16* __restrict__ XT,
    const float* __restrict__ Whh0, const float* __restrict__ Wih0,
    const float* __restrict__ bih0, const float* __restrict__ bhh0,
    const float* __restrict__ Wih1, const float* __restrict__ Whh1,
    const float* __restrict__ bih1, const float* __restrict__ bhh1,
    float* __restrict__ Out, f16* H0g, u32* Flags)
{
    const int layer = blockIdx.x >> 1;
    const int grp   = blockIdx.x & 1;
    const int t0 = threadIdx.x;
    const int w  = t0 >> 6;        // wave 0..7
    const int l  = t0 & 63;
    const int n  = l & 15;         // batch (within group): A-row / B-col / D-col
    const int q  = l >> 4;         // 0..3: k-group (in) / row-group (out)
    const int U0 = 16 * w + q * 4; // first unit this lane updates

    u32* F0 = Flags + (size_t)grp * 16;
    f16* H0 = H0g + (size_t)grp * TLEN * GB * HID;

    if (layer == 0) {
        __shared__ alignas(16) f16 hbuf[2][GB * HPAD];
        __shared__ alignas(16) f16 xc[CHK][GB * XPAD];

        // ---- pack A fragments: row = 16w + n + 128f, k = ks*32 + q*8 + i ----
        h8 wh[4][4], wx[4][2];
        #pragma unroll
        for (int f = 0; f < 4; ++f) {
            const int row = 16 * w + n + 128 * f;
            #pragma unroll
            for (int ks = 0; ks < 4; ++ks) {
                const float* s = Whh0 + (size_t)row * HID + ks * 32 + q * 8;
                h8 v;
                #pragma unroll
                for (int i = 0; i < 8; ++i) v[i] = (f16)s[i];
                wh[f][ks] = v;
            }
            #pragma unroll
            for (int ks = 0; ks < 2; ++ks) {
                const float* s = Wih0 + (size_t)row * DIN + ks * 32 + q * 8;
                h8 v;
                #pragma unroll
                for (int i = 0; i < 8; ++i) v[i] = (f16)s[i];
                wx[f][ks] = v;
            }
        }
        #pragma unroll
        for (int f = 0; f < 4; ++f) {
            #pragma unroll
            for (int ks = 0; ks < 4; ++ks) asm volatile("" : "+a"(wh[f][ks]));
            #pragma unroll
            for (int ks = 0; ks < 2; ++ks) asm volatile("" : "+a"(wx[f][ks]));
        }
        // bias for the D rows this lane owns
        f32x4 bias[4];
        #pragma unroll
        for (int f = 0; f < 4; ++f)
            #pragma unroll
            for (int r = 0; r < 4; ++r) {
                const int row = U0 + r + 128 * f;
                bias[f][r] = bih0[row] + bhh0[row];
            }

        for (int i = t0; i < GB * HPAD; i += 512) {
            hbuf[0][i] = (f16)0.0f; hbuf[1][i] = (f16)0.0f;
        }
        float cst[4] = {0.0f, 0.0f, 0.0f, 0.0f};
        __syncthreads();

        for (int tc = 0; tc < TLEN / CHK; ++tc) {
            const int tbase = tc * CHK;
            // stage x chunk: XT[t][grp*GB + b][64] f16 -> xc[s][b][XPAD]
            {
                const u32* src = (const u32*)XT;
                u32* dst = (u32*)&xc[0][0];
                for (int idx = t0; idx < CHK * GB * 32; idx += 512) {
                    const int s  = idx >> 9;           // /(GB*32)
                    const int rm = idx & 511;
                    const int b  = rm >> 5, cc = rm & 31;
                    dst[s * (GB * (XPAD / 2)) + b * (XPAD / 2) + cc] =
                        src[((size_t)(tbase + s) * BATCH + grp * GB + b) * 32 + cc];
                }
            }
            __syncthreads();

            #pragma unroll 1
            for (int s = 0; s < CHK; ++s) {
                const int t = tbase + s;
                const int cur = t & 1, prv = cur ^ 1;

                h8 bh[4], bx[2];
                #pragma unroll
                for (int ks = 0; ks < 4; ++ks)
                    bh[ks] = *(const h8*)&hbuf[prv][n * HPAD + ks * 32 + q * 8];
                #pragma unroll
                for (int ks = 0; ks < 2; ++ks)
                    bx[ks] = *(const h8*)&xc[s][n * XPAD + ks * 32 + q * 8];

                f32x4 acc[4];
                #pragma unroll
                for (int f = 0; f < 4; ++f) acc[f] = bias[f];
                #pragma unroll
                for (int ks = 0; ks < 4; ++ks)
                    #pragma unroll
                    for (int f = 0; f < 4; ++f)
                        acc[f] = __builtin_amdgcn_mfma_f32_16x16x32_f16(
                            wh[f][ks], bh[ks], acc[f], 0, 0, 0);
                #pragma unroll
                for (int ks = 0; ks < 2; ++ks)
                    #pragma unroll
                    for (int f = 0; f < 4; ++f)
                        acc[f] = __builtin_amdgcn_mfma_f32_16x16x32_f16(
                            wx[f][ks], bx[ks], acc[f], 0, 0, 0);

                // cell update: lane owns (units U0..U0+3, batch n)
                f16 hv[4];
                #pragma unroll
                for (int r = 0; r < 4; ++r) {
                    float ig = sigm(acc[0][r]);
                    float fg = sigm(acc[1][r]);
                    float gg = tanh_c(acc[2][r]);
                    float og = sigm(acc[3][r]);
                    cst[r] = fg * cst[r] + ig * gg;
                    hv[r] = (f16)(og * tanh_c(cst[r]));
                }
                h2 plo, phi;
                plo.x = hv[0]; plo.y = hv[1]; phi.x = hv[2]; phi.y = hv[3];
                const u32 ulo = __builtin_bit_cast(u32, plo);
                const u32 uhi = __builtin_bit_cast(u32, phi);
                // h -> LDS [batch n][U0..U0+4)
                uint2* dl = (uint2*)&hbuf[cur][n * HPAD + U0];
                *dl = make_uint2(ulo, uhi);
                // publish h0(t) -> global (2 u32 relaxed; flag release orders)
                u32* gp = (u32*)&H0[((size_t)t * GB + n) * HID + U0];
                astore_rlx(gp, ulo);
                astore_rlx(gp + 1, uhi);
                __syncthreads();
            }
            if (t0 == 0) astore_rel(F0, (u32)(tbase + CHK));
        }
    } else {
        // ------------------------- layer 1 -------------------------
        __shared__ alignas(16) f16 hbuf[2][GB * HPAD];
        __shared__ alignas(16) f16 h0c[CHK][GB * HPAD];

        h8 wa[4][8];   // ks 0..3: Wih1 (vs h0), ks 4..7: Whh1 (vs h1)
        #pragma unroll
        for (int f = 0; f < 4; ++f) {
            const int row = 16 * w + n + 128 * f;
            #pragma unroll
            for (int ks = 0; ks < 4; ++ks) {
                const float* s0 = Wih1 + (size_t)row * HID + ks * 32 + q * 8;
                const float* s1 = Whh1 + (size_t)row * HID + ks * 32 + q * 8;
                h8 v0, v1;
                #pragma unroll
                for (int i = 0; i < 8; ++i) { v0[i] = (f16)s0[i]; v1[i] = (f16)s1[i]; }
                wa[f][ks] = v0; wa[f][ks + 4] = v1;
            }
        }
        #pragma unroll
        for (int f = 0; f < 4; ++f)
            #pragma unroll
            for (int ks = 0; ks < 8; ++ks) asm volatile("" : "+a"(wa[f][ks]));

        f32x4 bias[4];
        #pragma unroll
        for (int f = 0; f < 4; ++f)
            #pragma unroll
            for (int r = 0; r < 4; ++r) {
                const int row = U0 + r + 128 * f;
                bias[f][r] = bih1[row] + bhh1[row];
            }

        for (int i = t0; i < GB * HPAD; i += 512) {
            hbuf[0][i] = (f16)0.0f; hbuf[1][i] = (f16)0.0f;
        }
        float cst[4] = {0.0f, 0.0f, 0.0f, 0.0f};
        __syncthreads();

        for (int tc = 0; tc < TLEN / CHK; ++tc) {
            const int tbase = tc * CHK;
            if (t0 == 0) {
                u32 av; long g = 0;
                do { av = aload_acq(F0);
                     if (av >= (u32)(tbase + CHK)) break;
                     __builtin_amdgcn_s_sleep(2);
                } while (++g < 50000000L);
            }
            __syncthreads();
            // stage h0 chunk -> LDS [s][b][HPAD]
            {
                const u32* src = (const u32*)H0;
                u32* dst = (u32*)&h0c[0][0];
                for (int idx = t0; idx < CHK * GB * 64; idx += 512) {
                    const int s  = idx >> 10;          // /(GB*64)
                    const int rm = idx & 1023;
                    const int b  = rm >> 6, cc = rm & 63;
                    dst[s * (GB * (HPAD / 2)) + b * (HPAD / 2) + cc] =
                        aload_rlx(&src[((size_t)(tbase + s) * GB + b) * 64 + cc]);
                }
            }
            __syncthreads();

            #pragma unroll 1
            for (int s = 0; s < CHK; ++s) {
                const int t = tbase + s;
                const int cur = t & 1, prv = cur ^ 1;

                h8 b0[4], b1[4];
                #pragma unroll
                for (int ks = 0; ks < 4; ++ks) {
                    b0[ks] = *(const h8*)&h0c[s][n * HPAD + ks * 32 + q * 8];
                    b1[ks] = *(const h8*)&hbuf[prv][n * HPAD + ks * 32 + q * 8];
                }
                f32x4 acc[4];
                #pragma unroll
                for (int f = 0; f < 4; ++f) acc[f] = bias[f];
                #pragma unroll
                for (int ks = 0; ks < 4; ++ks)
                    #pragma unroll
                    for (int f = 0; f < 4; ++f)
                        acc[f] = __builtin_amdgcn_mfma_f32_16x16x32_f16(
                            wa[f][ks], b0[ks], acc[f], 0, 0, 0);
                #pragma unroll
                for (int ks = 0; ks < 4; ++ks)
                    #pragma unroll
                    for (int f = 0; f < 4; ++f)
                        acc[f] = __builtin_amdgcn_mfma_f32_16x16x32_f16(
                            wa[f][ks + 4], b1[ks], acc[f], 0, 0, 0);

                f16 hv[4];
                f4 ov;
                #pragma unroll
                for (int r = 0; r < 4; ++r) {
                    float ig = sigm(acc[0][r]);
                    float fg = sigm(acc[1][r]);
                    float gg = tanh_c(acc[2][r]);
                    float og = sigm(acc[3][r]);
                    cst[r] = fg * cst[r] + ig * gg;
                    const float h1v = og * tanh_c(cst[r]);
                    hv[r] = (f16)h1v;
                    ov[r] = h1v;
                }
                h2 plo, phi;
                plo.x = hv[0]; plo.y = hv[1]; phi.x = hv[2]; phi.y = hv[3];
                uint2* dl = (uint2*)&hbuf[cur][n * HPAD + U0];
                *dl = make_uint2(__builtin_bit_cast(u32, plo),
                                 __builtin_bit_cast(u32, phi));
                // output: batch grp*GB+n, units U0..U0+3 (16B aligned)
                *(f4*)&Out[((size_t)(grp * GB + n) * TLEN + t) * HID + U0] = ov;
                __syncthreads();
            }
        }
    }
}

// ============================================================================
// Fallback (ws too small): round-1 kernel, known-correct at 6.8 ms.
// ============================================================================
__global__ __launch_bounds__(512, 2) void lstm2_persist(
    const float* __restrict__ X,
    const float* __restrict__ Wih0, const float* __restrict__ Whh0,
    const float* __restrict__ bih0, const float* __restrict__ bhh0,
    const float* __restrict__ Wih1, const float* __restrict__ Whh1,
    const float* __restrict__ bih1, const float* __restrict__ bhh1,
    float* __restrict__ Out)
{
    __shared__ unsigned int wih0_lds[512 * 33];
    __shared__ f16 h0buf[2][HID];
    __shared__ f16 h1buf[2][HID];

    const int b  = blockIdx.x;
    const int t  = threadIdx.x;
    const int rg = t >> 2;
    const int kg = t & 3;

    {
        const float2* src = (const float2*)(Wih0 + t * DIN);
        #pragma unroll
        for (int i = 0; i < 32; ++i) {
            float2 v = src[i];
            h2 p; p.x = (f16)v.x; p.y = (f16)v.y;
            wih0_lds[t * 33 + i] = __builtin_bit_cast(unsigned int, p);
        }
    }
    if (t < HID) {
        h0buf[0][t] = (f16)0.0f; h0buf[1][t] = (f16)0.0f;
        h1buf[0][t] = (f16)0.0f; h1buf[1][t] = (f16)0.0f;
    }

    h2 whh0[4][16], wih1[4][16], whh1[4][16];
    float bi0[4], bi1[4];
    #pragma unroll
    for (int m = 0; m < 4; ++m) {
        const int row = rg + 128 * m;
        const float2* a = (const float2*)(Whh0 + row * HID + kg * 32);
        const float2* c = (const float2*)(Wih1 + row * HID + kg * 32);
        const float2* d = (const float2*)(Whh1 + row * HID + kg * 32);
        #pragma unroll
        for (int i = 0; i < 16; ++i) {
            float2 v; h2 w;
            v = a[i]; w.x = (f16)v.x; w.y = (f16)v.y; whh0[m][i] = w;
            v = c[i]; w.x = (f16)v.x; w.y = (f16)v.y; wih1[m][i] = w;
            v = d[i]; w.x = (f16)v.x; w.y = (f16)v.y; whh1[m][i] = w;
        }
        bi0[m] = (kg == 0) ? (bih0[row] + bhh0[row]) : 0.0f;
        bi1[m] = (kg == 0) ? (bih1[row] + bhh1[row]) : 0.0f;
    }

    float c0 = 0.0f, c1 = 0.0f;
    __syncthreads();

    f4 xA[4], xB[4];
    {
        const f4* xp = (const f4*)(X + ((size_t)b * TLEN) * DIN + kg * 16);
        #pragma unroll
        for (int j = 0; j < 4; ++j) xA[j] = xp[j];
    }

    auto step = [&](int tt, f4 (&xc)[4], f4 (&xn)[4]) {
        const int cur = tt & 1, nxt = cur ^ 1;
        h2 xh[8];
        const float* xf = (const float*)xc;
        #pragma unroll
        for (int j = 0; j < 8; ++j) {
            h2 p; p.x = (f16)xf[2 * j]; p.y = (f16)xf[2 * j + 1];
            xh[j] = p;
        }
        {
            const int tn = (tt + 1 < TLEN) ? tt + 1 : TLEN - 1;
            const f4* xp = (const f4*)(X + ((size_t)b * TLEN + tn) * DIN + kg * 16);
            #pragma unroll
            for (int j = 0; j < 4; ++j) xn[j] = xp[j];
        }
        float p0[4];
        #pragma unroll
        for (int m = 0; m < 4; ++m) p0[m] = bi0[m];
        #pragma unroll
        for (int m = 0; m < 4; ++m) {
            const unsigned int* wr = &wih0_lds[(rg + 128 * m) * 33 + kg * 8];
            #pragma unroll
            for (int i = 0; i < 8; ++i) {
                h2 w = __builtin_bit_cast(h2, wr[i]);
                p0[m] = FDOT2(w, xh[i], p0[m]);
            }
        }
        {
            const unsigned int* hr = (const unsigned int*)&h0buf[cur][0];
            #pragma unroll
            for (int i = 0; i < 16; ++i) {
                h2 hv = __builtin_bit_cast(h2, hr[kg * 16 + i]);
                #pragma unroll
                for (int m = 0; m < 4; ++m)
                    p0[m] = FDOT2(whh0[m][i], hv, p0[m]);
            }
        }
        #pragma unroll
        for (int m = 0; m < 4; ++m) {
            p0[m] += __shfl_xor(p0[m], 1, 4);
            p0[m] += __shfl_xor(p0[m], 2, 4);
        }
        {
            float ii = sigm(p0[0]), ff = sigm(p0[1]);
            float gg = tanh_c(p0[2]), oo = sigm(p0[3]);
            c0 = ff * c0 + ii * gg;
            float h0v = oo * tanh_c(c0);
            if (kg == 0) h0buf[nxt][rg] = (f16)h0v;
        }
        __syncthreads();
        float q[4];
        #pragma unroll
        for (int m = 0; m < 4; ++m) q[m] = bi1[m];
        {
            const unsigned int* hr = (const unsigned int*)&h0buf[nxt][0];
            #pragma unroll
            for (int i = 0; i < 16; ++i) {
                h2 hv = __builtin_bit_cast(h2, hr[kg * 16 + i]);
                #pragma unroll
                for (int m = 0; m < 4; ++m)
                    q[m] = FDOT2(wih1[m][i], hv, q[m]);
            }
        }
        {
            const unsigned int* hr = (const unsigned int*)&h1buf[cur][0];
            #pragma unroll
            for (int i = 0; i < 16; ++i) {
                h2 hv = __builtin_bit_cast(h2, hr[kg * 16 + i]);
                #pragma unroll
                for (int m = 0; m < 4; ++m)
                    q[m] = FDOT2(whh1[m][i], hv, q[m]);
            }
        }
        #pragma unroll
        for (int m = 0; m < 4; ++m) {
            q[m] += __shfl_xor(q[m], 1, 4);
            q[m] += __shfl_xor(q[m], 2, 4);
        }
        {
            float ii = sigm(q[0]), ff = sigm(q[1]);
            float gg = tanh_c(q[2]), oo = sigm(q[3]);
            c1 = ff * c1 + ii * gg;
            float h1v = oo * tanh_c(c1);
            if (kg == 0) {
                h1buf[nxt][rg] = (f16)h1v;
                Out[((size_t)b * TLEN + tt) * HID + rg] = h1v;
            }
        }
        __syncthreads();
    };

    for (int tt = 0; tt < TLEN; tt += 2) {
        step(tt, xA, xB);
        step(tt + 1, xB, xA);
    }
}

extern "C" void kernel_launch(void* const* d_in, const int* in_sizes, int n_in,
                              void* d_out, int out_size, void* d_ws, size_t ws_size,
                              hipStream_t stream) {
    const float* X    = (const float*)d_in[0];
    const float* Wih0 = (const float*)d_in[1];
    const float* Whh0 = (const float*)d_in[2];
    const float* bih0 = (const float*)d_in[3];
    const float* bhh0 = (const float*)d_in[4];
    const float* Wih1 = (const float*)d_in[5];
    const float* Whh1 = (const float*)d_in[6];
    const float* bih1 = (const float*)d_in[7];
    const float* bhh1 = (const float*)d_in[8];
    float* Out = (float*)d_out;

    const size_t XT_B   = (size_t)TLEN * BATCH * DIN * 2;        // 8 MiB
    const size_t H0_B   = (size_t)2 * TLEN * GB * HID * 2;       // 16 MiB
    const size_t FLAG_B = 2 * 16 * 4;
    const size_t NEED   = XT_B + H0_B + FLAG_B;

    if (ws_size >= NEED) {
        char* ws = (char*)d_ws;
        f16* XT    = (f16*)ws;
        f16* H0g   = (f16*)(ws + XT_B);
        u32* Flags = (u32*)(ws + XT_B + H0_B);

        hipMemsetAsync(Flags, 0, FLAG_B, stream);   // re-arm sync every launch
        xt_precompute<<<dim3(TLEN), dim3(256), 0, stream>>>(X, XT);
        lstm2_mfma<<<dim3(4), dim3(512), 0, stream>>>(
            XT, Whh0, Wih0, bih0, bhh0, Wih1, Whh1, bih1, bhh1,
            Out, H0g, Flags);
    } else {
        lstm2_persist<<<dim3(BATCH), dim3(512), 0, stream>>>(
            X, Wih0, Whh0, bih0, bhh0, Wih1, Whh1, bih1, bhh1, Out);
    }
}

// Round 16
// 2095.963 us; speedup vs baseline: 1.5612x; 1.5612x over previous
//
#include <hip/hip_runtime.h>

#define TLEN 2048
#define BATCH 32
#define DIN 64
#define HID 128
#define RING 256   // xg1 ring depth (steps); power of 2, multiple of CHK
#define CHK 8      // pipeline chunk (steps)
#define WRS 68     // LDS weight row stride in dwords (64 data + 4 pad)

typedef _Float16 f16;
typedef _Float16 h2 __attribute__((ext_vector_type(2)));
typedef float f4 __attribute__((ext_vector_type(4)));
typedef unsigned int u32;

#if defined(__has_builtin)
#if __has_builtin(__builtin_amdgcn_fdot2)
#define FDOT2(a, b, c) __builtin_amdgcn_fdot2((a), (b), (c), false)
#endif
#endif
#ifndef FDOT2
#define FDOT2(a, b, c) ((c) + (float)(a).x * (float)(b).x + (float)(a).y * (float)(b).y)
#endif
#define DOT2U(wu, hv, acc) FDOT2(__builtin_bit_cast(h2, (wu)), (hv), (acc))

// ---- fast activations (R12/R14-proven; absmax unchanged) ----
#if defined(__has_builtin)
#if __has_builtin(__builtin_amdgcn_exp2f)
#define FEXP2(x) __builtin_amdgcn_exp2f(x)
#endif
#if __has_builtin(__builtin_amdgcn_rcpf)
#define FRCP(x) __builtin_amdgcn_rcpf(x)
#endif
#endif
#ifndef FEXP2
#define FEXP2(x) __expf((x) * 0.69314718f)
#endif
#ifndef FRCP
#define FRCP(x) (1.0f / (x))
#endif

__device__ __forceinline__ float sigm(float x) {
    return FRCP(1.0f + FEXP2(-1.44269504f * x));
}
__device__ __forceinline__ float tanh_c(float x) {
    x = fminf(fmaxf(x, -15.0f), 15.0f);
    float e = FEXP2(2.88539008f * x);
    return (e - 1.0f) * FRCP(e + 1.0f);
}

// ---- quad butterfly via DPP quad_perm (VALU pipe, NOT the LDS pipe) ----
// R14's __shfl_xor(v,1,4)/(v,2,4) lower to ds_bpermute/ds_swizzle and share
// the LDS pipe with the weight stream (the step bottleneck). quad_perm moves
// the 8 ops/thread/step to the VALU. Single-variable change vs R14.
// 0xB1 = [1,0,3,2] (xor 1), 0x4E = [2,3,0,1] (xor 2); old=src, bound_ctrl=0.
__device__ __forceinline__ float qswap1_dpp(float v) {
    const int s = __builtin_bit_cast(int, v);
    return __builtin_bit_cast(float,
        __builtin_amdgcn_update_dpp(s, s, 0xB1, 0xF, 0xF, false));
}
__device__ __forceinline__ float qswap2_dpp(float v) {
    const int s = __builtin_bit_cast(int, v);
    return __builtin_bit_cast(float,
        __builtin_amdgcn_update_dpp(s, s, 0x4E, 0xF, 0xF, false));
}
__device__ __forceinline__ void qreduce(float (&v)[4]) {
    #pragma unroll
    for (int m = 0; m < 4; ++m) {
        v[m] += qswap1_dpp(v[m]);
        v[m] += qswap2_dpp(v[m]);
    }
}

// agent-scope atomics (R8/R9-proven cross-XCD path)
__device__ __forceinline__ u32 aload_rlx(const u32* p) {
    return __hip_atomic_load(p, __ATOMIC_RELAXED, __HIP_MEMORY_SCOPE_AGENT);
}
__device__ __forceinline__ u32 aload_acq(const u32* p) {
    return __hip_atomic_load(p, __ATOMIC_ACQUIRE, __HIP_MEMORY_SCOPE_AGENT);
}
__device__ __forceinline__ void astore_rlx(u32* p, u32 v) {
    __hip_atomic_store(p, v, __ATOMIC_RELAXED, __HIP_MEMORY_SCOPE_AGENT);
}
__device__ __forceinline__ void astore_rel(u32* p, u32 v) {
    __hip_atomic_store(p, v, __ATOMIC_RELEASE, __HIP_MEMORY_SCOPE_AGENT);
}

// stage gate-rows m=0,1 (rows 0..255) of a 512x128 f32 matrix -> LDS f16 pairs
__device__ __forceinline__ void stage_w2(const float* __restrict__ W,
                                         u32* __restrict__ wl, int t0) {
    const float2* src2 = (const float2*)W;
    for (int idx = t0; idx < 256 * 64; idx += 512) {
        const int row = idx >> 6, d = idx & 63;
        float2 v = src2[(size_t)row * 64 + d];
        h2 x; x.x = (f16)v.x; x.y = (f16)v.y;
        wl[(size_t)row * WRS + d] = __builtin_bit_cast(u32, x);
    }
}

// gates m=2,3 weight slice -> registers (32 dwords), pinned once (R14 as-is).
__device__ __forceinline__ void load_w_m23(const float* __restrict__ W,
                                           int rg, int kg, u32 (&w)[32]) {
    #pragma unroll
    for (int mh = 0; mh < 2; ++mh) {
        const float2* a =
            (const float2*)(W + (size_t)(rg + 128 * (2 + mh)) * HID + kg * 32);
        #pragma unroll
        for (int i = 0; i < 16; ++i) {
            float2 v = a[i];
            h2 x; x.x = (f16)v.x; x.y = (f16)v.y;
            w[mh * 16 + i] = __builtin_bit_cast(u32, x);
        }
    }
    #pragma unroll
    for (int i = 0; i < 32; ++i) asm volatile("" : "+v"(w[i]));
}

// One step's 4-gate dot for thread (rg,kg)  (R14 as-is).
__device__ __forceinline__ void dot_split(const u32* __restrict__ wl,
                                          int rg, int kg,
                                          const u32* __restrict__ hsl,
                                          const u32 (&wr)[32],
                                          float (&p)[4]) {
    uint4 hq[4];
    #pragma unroll
    for (int i4 = 0; i4 < 4; ++i4) hq[i4] = *(const uint4*)&hsl[i4 * 4];

    // LDS gates m = 0,1
    #pragma unroll
    for (int m = 0; m < 2; ++m) {
        const u32* wb = wl + (size_t)(rg + 128 * m) * WRS + kg * 16;
        #pragma unroll
        for (int i4 = 0; i4 < 4; ++i4) {
            const uint4 wv = *(const uint4*)&wb[i4 * 4];
            const u32* hw = (const u32*)&hq[i4];
            p[m] = DOT2U(wv.x, __builtin_bit_cast(h2, hw[0]), p[m]);
            p[m] = DOT2U(wv.y, __builtin_bit_cast(h2, hw[1]), p[m]);
            p[m] = DOT2U(wv.z, __builtin_bit_cast(h2, hw[2]), p[m]);
            p[m] = DOT2U(wv.w, __builtin_bit_cast(h2, hw[3]), p[m]);
        }
    }
    // register gates m = 2,3
    #pragma unroll
    for (int mh = 0; mh < 2; ++mh) {
        #pragma unroll
        for (int i4 = 0; i4 < 4; ++i4) {
            const u32* hw = (const u32*)&hq[i4];
            #pragma unroll
            for (int j = 0; j < 4; ++j)
                p[2 + mh] = DOT2U(wr[mh * 16 + i4 * 4 + j],
                                  __builtin_bit_cast(h2, hw[j]), p[2 + mh]);
        }
    }
}

// ============================================================================
// Kernel 1: XG0[b,t,j] = Wih0[row_j]·x[b,t] + bih0[row_j] + bhh0[row_j], f16.
// ============================================================================
__global__ __launch_bounds__(512) void xg_precompute(
    const float* __restrict__ X, const float* __restrict__ Wih0,
    const float* __restrict__ bih0, const float* __restrict__ bhh0,
    f16* __restrict__ XG)
{
    __shared__ float xs[16][DIN];
    const int blk = blockIdx.x;               // over B * (T/16)
    const int b   = blk / (TLEN / 16);
    const int tc  = blk % (TLEN / 16);
    const int j   = threadIdx.x;
    const int row = (j >> 2) + 128 * (j & 3);

    const float* xsrc = X + ((size_t)b * TLEN + (size_t)tc * 16) * DIN;
    for (int i = j; i < 16 * DIN; i += 512) ((float*)xs)[i] = xsrc[i];
    __syncthreads();

    f4 w[16];
    const f4* wp = (const f4*)(Wih0 + (size_t)row * DIN);
    #pragma unroll
    for (int i = 0; i < 16; ++i) w[i] = wp[i];
    const float bias = bih0[row] + bhh0[row];

    f16* dst = XG + ((size_t)b * TLEN + (size_t)tc * 16) * 512 + j;
    #pragma unroll 4
    for (int t = 0; t < 16; ++t) {
        float acc = bias;
        const f4* xv = (const f4*)&xs[t][0];
        #pragma unroll
        for (int i = 0; i < 16; ++i) {
            f4 x4 = xv[i];
            acc += w[i][0] * x4[0] + w[i][1] * x4[1] + w[i][2] * x4[2] + w[i][3] * x4[3];
        }
        dst[(size_t)t * 512] = (f16)acc;
    }
}

// ============================================================================
// Kernel 2: 3-stage pipeline (R14 structure verbatim; only qreduce changed).
// grid = 96: role = bid/32, batch = bid%32. Thread: rg = t0>>2, kg = t0&3.
// ============================================================================
__global__ __launch_bounds__(512, 1) void lstm2_pipe(
    const f16* __restrict__ XG0,
    const float* __restrict__ Whh0,
    const float* __restrict__ Wih1, const float* __restrict__ Whh1,
    const float* __restrict__ bih1, const float* __restrict__ bhh1,
    float* __restrict__ Out,
    u32* __restrict__ H0g,     // [BATCH][TLEN][64] u32 (f16 pairs)
    u32* __restrict__ XG1,     // [BATCH][RING][512] u32 (f32 bits)
    u32* __restrict__ Flags)   // 96 slots x 16 u32
{
    __shared__ alignas(16) u32 pool[21632];

    const int role = blockIdx.x / BATCH;
    const int b    = blockIdx.x % BATCH;
    const int t0   = threadIdx.x;
    const int rg   = t0 >> 2;
    const int kg   = t0 & 3;

    u32* F0 = Flags + (size_t)b * 16;
    u32* F1 = Flags + (size_t)(32 + b) * 16;
    u32* C2 = Flags + (size_t)(64 + b) * 16;

    if (role == 0) {
        // ---------------- layer-0 cell ----------------
        stage_w2(Whh0, pool, t0);
        u32 wr[32];
        load_w_m23(Whh0, rg, kg, wr);
        u32* hl = pool + 17408;               // [2][64] dwords (f16 pairs)
        if (t0 < 128) hl[t0] = 0u;
        float c0 = 0.0f;
        const f16* xgp = XG0 + (size_t)b * TLEN * 512 + t0;
        u32* h0out = H0g + (size_t)b * TLEN * 64;
        f16 xga = xgp[0];
        f16 xgb = xgp[512];
        __syncthreads();

        for (int t = 0; t < TLEN; ++t) {
            const int cur = t & 1, prv = cur ^ 1;
            const float xgv = (float)xga;
            xga = xgb;
            { int tn = (t + 2 < TLEN) ? t + 2 : TLEN - 1; xgb = xgp[(size_t)tn * 512]; }

            float p[4];
            #pragma unroll
            for (int m = 0; m < 4; ++m) p[m] = (kg == m) ? xgv : 0.0f;
            dot_split(pool, rg, kg, hl + prv * 64 + kg * 16, wr, p);
            qreduce(p);
            float ii = sigm(p[0]), ff = sigm(p[1]);
            float gg = tanh_c(p[2]), oo = sigm(p[3]);
            c0 = ff * c0 + ii * gg;
            if (kg == 0) {
                f16* hf = (f16*)(hl + cur * 64);
                hf[rg] = (f16)(oo * tanh_c(c0));
            }
            __syncthreads();
            if (t0 < 64)
                astore_rlx(&h0out[(size_t)t * 64 + t0], hl[cur * 64 + t0]);
            if (t0 == 0 && (t & (CHK - 1)) == (CHK - 1))
                astore_rel(F0, (u32)(t + 1));
        }
    } else if (role == 1) {
        // ---------------- xg1 producer, chunk-prefetched ----------------
        stage_w2(Wih1, pool, t0);
        u32 wr[32];
        load_w_m23(Wih1, rg, kg, wr);
        u32* h0c = pool + 17408;              // [CHK*64] dwords
        const int rowk = rg + 128 * kg;
        const float B1 = bih1[rowk] + bhh1[rowk];
        u32* H0in = H0g + (size_t)b * TLEN * 64;
        u32* xout = XG1 + (size_t)b * RING * 512;
        u32 sc = 0;
        __syncthreads();

        for (int c = 0; c < TLEN / CHK; ++c) {
            const int tbase = c * CHK;
            if (t0 == 0) {
                u32 av; long g = 0;
                do { av = aload_acq(F0);
                     if (av >= (u32)(tbase + CHK)) break;
                     __builtin_amdgcn_s_sleep(2);
                } while (++g < 50000000L);
                if (tbase + CHK > (int)sc + (RING - 64)) {     // backpressure
                    g = 0;
                    do { sc = aload_rlx(C2);
                         if (tbase + CHK <= (int)sc + (RING - 64)) break;
                         __builtin_amdgcn_s_sleep(2);
                    } while (++g < 50000000L);
                }
            }
            __syncthreads();                        // poll done; h0c reusable
            h0c[t0] = aload_rlx(&H0in[(size_t)tbase * 64 + t0]);  // 512 = CHK*64
            __syncthreads();

            #pragma unroll
            for (int s = 0; s < CHK; ++s) {
                const int t = tbase + s;
                float p[4];
                #pragma unroll
                for (int m = 0; m < 4; ++m) p[m] = (kg == m) ? B1 : 0.0f;
                dot_split(pool, rg, kg, h0c + s * 64 + kg * 16, wr, p);
                qreduce(p);
                astore_rlx(&xout[(size_t)(t & (RING - 1)) * 512 + t0],
                           __builtin_bit_cast(u32, p[kg]));
            }
            asm volatile("s_waitcnt vmcnt(0)" ::: "memory");
            __syncthreads();
            if (t0 == 0) astore_rel(F1, (u32)(tbase + CHK));
        }
    } else {
        // ---------------- layer-1 cell, chunk-prefetched ----------------
        stage_w2(Whh1, pool, t0);
        u32 wr[32];
        load_w_m23(Whh1, rg, kg, wr);
        u32* xgc = pool + 17408;              // [CHK*512] dwords
        u32* hl  = pool + 21504;              // [2][64] dwords
        if (t0 < 128) hl[t0] = 0u;
        u32* xin = XG1 + (size_t)b * RING * 512;
        float c1 = 0.0f;
        __syncthreads();

        for (int c = 0; c < TLEN / CHK; ++c) {
            const int tbase = c * CHK;
            if (t0 == 0) {
                u32 av; long g = 0;
                do { av = aload_acq(F1);
                     if (av >= (u32)(tbase + CHK)) break;
                     __builtin_amdgcn_s_sleep(2);
                } while (++g < 50000000L);
            }
            __syncthreads();
            const size_t rbase = (size_t)(tbase & (RING - 1)) * 512;
            #pragma unroll
            for (int k = 0; k < CHK; ++k)
                xgc[k * 512 + t0] = aload_rlx(&xin[rbase + k * 512 + t0]);
            __syncthreads();

            #pragma unroll 1
            for (int s = 0; s < CHK; ++s) {
                const int t = tbase + s;
                const int cur = t & 1, prv = cur ^ 1;
                const float xgv = __builtin_bit_cast(float, xgc[s * 512 + t0]);

                float q[4];
                #pragma unroll
                for (int m = 0; m < 4; ++m) q[m] = (kg == m) ? xgv : 0.0f;
                dot_split(pool, rg, kg, hl + prv * 64 + kg * 16, wr, q);
                qreduce(q);
                float ii = sigm(q[0]), ff = sigm(q[1]);
                float gg = tanh_c(q[2]), oo = sigm(q[3]);
                c1 = ff * c1 + ii * gg;
                float h1v = oo * tanh_c(c1);
                if (kg == 0) {
                    f16* hf = (f16*)(hl + cur * 64);
                    hf[rg] = (f16)h1v;
                    Out[((size_t)b * TLEN + t) * HID + rg] = h1v;
                }
                __syncthreads();
            }
            if (t0 == 0 && (c & 3) == 3)
                astore_rlx(C2, (u32)(tbase + CHK));
        }
    }
}

// ============================================================================
// Fallback (ws too small): round-1 kernel structure, known-correct (shfl).
// ============================================================================
__global__ __launch_bounds__(512, 2) void lstm2_persist(
    const float* __restrict__ X,
    const float* __restrict__ Wih0, const float* __restrict__ Whh0,
    const float* __restrict__ bih0, const float* __restrict__ bhh0,
    const float* __restrict__ Wih1, const float* __restrict__ Whh1,
    const float* __restrict__ bih1, const float* __restrict__ bhh1,
    float* __restrict__ Out)
{
    __shared__ unsigned int wih0_lds[512 * 33];
    __shared__ f16 h0buf[2][HID];
    __shared__ f16 h1buf[2][HID];

    const int b  = blockIdx.x;
    const int t  = threadIdx.x;
    const int rg = t >> 2;
    const int kg = t & 3;

    {
        const float2* src = (const float2*)(Wih0 + t * DIN);
        #pragma unroll
        for (int i = 0; i < 32; ++i) {
            float2 v = src[i];
            h2 p; p.x = (f16)v.x; p.y = (f16)v.y;
            wih0_lds[t * 33 + i] = __builtin_bit_cast(unsigned int, p);
        }
    }
    if (t < HID) {
        h0buf[0][t] = (f16)0.0f; h0buf[1][t] = (f16)0.0f;
        h1buf[0][t] = (f16)0.0f; h1buf[1][t] = (f16)0.0f;
    }

    h2 whh0[4][16], wih1[4][16], whh1[4][16];
    float bi0[4], bi1[4];
    #pragma unroll
    for (int m = 0; m < 4; ++m) {
        const int row = rg + 128 * m;
        const float2* a = (const float2*)(Whh0 + row * HID + kg * 32);
        const float2* c = (const float2*)(Wih1 + row * HID + kg * 32);
        const float2* d = (const float2*)(Whh1 + row * HID + kg * 32);
        #pragma unroll
        for (int i = 0; i < 16; ++i) {
            float2 v; h2 w;
            v = a[i]; w.x = (f16)v.x; w.y = (f16)v.y; whh0[m][i] = w;
            v = c[i]; w.x = (f16)v.x; w.y = (f16)v.y; wih1[m][i] = w;
            v = d[i]; w.x = (f16)v.x; w.y = (f16)v.y; whh1[m][i] = w;
        }
        bi0[m] = (kg == 0) ? (bih0[row] + bhh0[row]) : 0.0f;
        bi1[m] = (kg == 0) ? (bih1[row] + bhh1[row]) : 0.0f;
    }

    float c0 = 0.0f, c1 = 0.0f;
    __syncthreads();

    f4 xA[4], xB[4];
    {
        const f4* xp = (const f4*)(X + ((size_t)b * TLEN) * DIN + kg * 16);
        #pragma unroll
        for (int j = 0; j < 4; ++j) xA[j] = xp[j];
    }

    auto step = [&](int tt, f4 (&xc)[4], f4 (&xn)[4]) {
        const int cur = tt & 1, nxt = cur ^ 1;
        h2 xh[8];
        const float* xf = (const float*)xc;
        #pragma unroll
        for (int j = 0; j < 8; ++j) {
            h2 p; p.x = (f16)xf[2 * j]; p.y = (f16)xf[2 * j + 1];
            xh[j] = p;
        }
        {
            const int tn = (tt + 1 < TLEN) ? tt + 1 : TLEN - 1;
            const f4* xp = (const f4*)(X + ((size_t)b * TLEN + tn) * DIN + kg * 16);
            #pragma unroll
            for (int j = 0; j < 4; ++j) xn[j] = xp[j];
        }
        float p0[4];
        #pragma unroll
        for (int m = 0; m < 4; ++m) p0[m] = bi0[m];
        #pragma unroll
        for (int m = 0; m < 4; ++m) {
            const unsigned int* wr = &wih0_lds[(rg + 128 * m) * 33 + kg * 8];
            #pragma unroll
            for (int i = 0; i < 8; ++i) {
                h2 w = __builtin_bit_cast(h2, wr[i]);
                p0[m] = FDOT2(w, xh[i], p0[m]);
            }
        }
        {
            const unsigned int* hr = (const unsigned int*)&h0buf[cur][0];
            #pragma unroll
            for (int i = 0; i < 16; ++i) {
                h2 hv = __builtin_bit_cast(h2, hr[kg * 16 + i]);
                #pragma unroll
                for (int m = 0; m < 4; ++m)
                    p0[m] = FDOT2(whh0[m][i], hv, p0[m]);
            }
        }
        #pragma unroll
        for (int m = 0; m < 4; ++m) {
            p0[m] += __shfl_xor(p0[m], 1, 4);
            p0[m] += __shfl_xor(p0[m], 2, 4);
        }
        {
            float ii = sigm(p0[0]), ff = sigm(p0[1]);
            float gg = tanh_c(p0[2]), oo = sigm(p0[3]);
            c0 = ff * c0 + ii * gg;
            float h0v = oo * tanh_c(c0);
            if (kg == 0) h0buf[nxt][rg] = (f16)h0v;
        }
        __syncthreads();
        float q[4];
        #pragma unroll
        for (int m = 0; m < 4; ++m) q[m] = bi1[m];
        {
            const unsigned int* hr = (const unsigned int*)&h0buf[nxt][0];
            #pragma unroll
            for (int i = 0; i < 16; ++i) {
                h2 hv = __builtin_bit_cast(h2, hr[kg * 16 + i]);
                #pragma unroll
                for (int m = 0; m < 4; ++m)
                    q[m] = FDOT2(wih1[m][i], hv, q[m]);
            }
        }
        {
            const unsigned int* hr = (const unsigned int*)&h1buf[cur][0];
            #pragma unroll
            for (int i = 0; i < 16; ++i) {
                h2 hv = __builtin_bit_cast(h2, hr[kg * 16 + i]);
                #pragma unroll
                for (int m = 0; m < 4; ++m)
                    q[m] = FDOT2(whh1[m][i], hv, q[m]);
            }
        }
        #pragma unroll
        for (int m = 0; m < 4; ++m) {
            q[m] += __shfl_xor(q[m], 1, 4);
            q[m] += __shfl_xor(q[m], 2, 4);
        }
        {
            float ii = sigm(q[0]), ff = sigm(q[1]);
            float gg = tanh_c(q[2]), oo = sigm(q[3]);
            c1 = ff * c1 + ii * gg;
            float h1v = oo * tanh_c(c1);
            if (kg == 0) {
                h1buf[nxt][rg] = (f16)h1v;
                Out[((size_t)b * TLEN + tt) * HID + rg] = h1v;
            }
        }
        __syncthreads();
    };

    for (int tt = 0; tt < TLEN; tt += 2) {
        step(tt, xA, xB);
        step(tt + 1, xB, xA);
    }
}

extern "C" void kernel_launch(void* const* d_in, const int* in_sizes, int n_in,
                              void* d_out, int out_size, void* d_ws, size_t ws_size,
                              hipStream_t stream) {
    const float* X    = (const float*)d_in[0];
    const float* Wih0 = (const float*)d_in[1];
    const float* Whh0 = (const float*)d_in[2];
    const float* bih0 = (const float*)d_in[3];
    const float* bhh0 = (const float*)d_in[4];
    const float* Wih1 = (const float*)d_in[5];
    const float* Whh1 = (const float*)d_in[6];
    const float* bih1 = (const float*)d_in[7];
    const float* bhh1 = (const float*)d_in[8];
    float* Out = (float*)d_out;

    const size_t XG0_B  = (size_t)BATCH * TLEN * 512 * 2;   // 64 MiB f16
    const size_t H0_B   = (size_t)BATCH * TLEN * 64 * 4;    // 16 MiB
    const size_t XG1_B  = (size_t)BATCH * RING * 512 * 4;   // 16 MiB
    const size_t FLAG_B = 96 * 16 * 4;
    const size_t NEED   = XG0_B + H0_B + XG1_B + FLAG_B;

    if (ws_size >= NEED) {
        char* ws = (char*)d_ws;
        f16* XG0   = (f16*)ws;
        u32* H0g   = (u32*)(ws + XG0_B);
        u32* XG1   = (u32*)(ws + XG0_B + H0_B);
        u32* Flags = (u32*)(ws + XG0_B + H0_B + XG1_B);

        hipMemsetAsync(Flags, 0, FLAG_B, stream);   // re-arm sync every launch
        xg_precompute<<<dim3(BATCH * (TLEN / 16)), dim3(512), 0, stream>>>(
            X, Wih0, bih0, bhh0, XG0);
        lstm2_pipe<<<dim3(3 * BATCH), dim3(512), 0, stream>>>(
            XG0, Whh0, Wih1, Whh1, bih1, bhh1, Out, H0g, XG1, Flags);
    } else {
        lstm2_persist<<<dim3(BATCH), dim3(512), 0, stream>>>(
            X, Wih0, Whh0, bih0, bhh0, Wih1, Whh1, bih1, bhh1, Out);
    }
}

// Round 18
// 2093.700 us; speedup vs baseline: 1.5629x; 1.0011x over previous
//
#include <hip/hip_runtime.h>

#define TLEN 2048
#define BATCH 32
#define DIN 64
#define HID 128
#define RING 256   // xg1 ring depth (steps); power of 2, multiple of CHK
#define CHK 8      // pipeline chunk (steps)
#define WRS 68     // LDS weight row stride in dwords (64 data + 4 pad)

typedef _Float16 f16;
typedef _Float16 h2 __attribute__((ext_vector_type(2)));
typedef float f4 __attribute__((ext_vector_type(4)));
typedef unsigned int u32;

#if defined(__has_builtin)
#if __has_builtin(__builtin_amdgcn_fdot2)
#define FDOT2(a, b, c) __builtin_amdgcn_fdot2((a), (b), (c), false)
#endif
#endif
#ifndef FDOT2
#define FDOT2(a, b, c) ((c) + (float)(a).x * (float)(b).x + (float)(a).y * (float)(b).y)
#endif
#define DOT2U(wu, hv, acc) FDOT2(__builtin_bit_cast(h2, (wu)), (hv), (acc))

// ---- fast activations (R12/R14-proven; absmax unchanged) ----
#if defined(__has_builtin)
#if __has_builtin(__builtin_amdgcn_exp2f)
#define FEXP2(x) __builtin_amdgcn_exp2f(x)
#endif
#if __has_builtin(__builtin_amdgcn_rcpf)
#define FRCP(x) __builtin_amdgcn_rcpf(x)
#endif
#endif
#ifndef FEXP2
#define FEXP2(x) __expf((x) * 0.69314718f)
#endif
#ifndef FRCP
#define FRCP(x) (1.0f / (x))
#endif

__device__ __forceinline__ float sigm(float x) {
    return FRCP(1.0f + FEXP2(-1.44269504f * x));
}
__device__ __forceinline__ float tanh_c(float x) {
    x = fminf(fmaxf(x, -15.0f), 15.0f);
    float e = FEXP2(2.88539008f * x);
    return (e - 1.0f) * FRCP(e + 1.0f);
}

// ---- quad butterfly via DPP quad_perm (R16-proven correct, VALU pipe) ----
__device__ __forceinline__ float qswap1_dpp(float v) {
    const int s = __builtin_bit_cast(int, v);
    return __builtin_bit_cast(float,
        __builtin_amdgcn_update_dpp(s, s, 0xB1, 0xF, 0xF, false));
}
__device__ __forceinline__ float qswap2_dpp(float v) {
    const int s = __builtin_bit_cast(int, v);
    return __builtin_bit_cast(float,
        __builtin_amdgcn_update_dpp(s, s, 0x4E, 0xF, 0xF, false));
}
__device__ __forceinline__ void qreduce(float (&v)[4]) {
    #pragma unroll
    for (int m = 0; m < 4; ++m) {
        v[m] += qswap1_dpp(v[m]);
        v[m] += qswap2_dpp(v[m]);
    }
}

// agent-scope atomics (R8/R9-proven cross-XCD path)
__device__ __forceinline__ u32 aload_rlx(const u32* p) {
    return __hip_atomic_load(p, __ATOMIC_RELAXED, __HIP_MEMORY_SCOPE_AGENT);
}
__device__ __forceinline__ u32 aload_acq(const u32* p) {
    return __hip_atomic_load(p, __ATOMIC_ACQUIRE, __HIP_MEMORY_SCOPE_AGENT);
}
__device__ __forceinline__ void astore_rlx(u32* p, u32 v) {
    __hip_atomic_store(p, v, __ATOMIC_RELAXED, __HIP_MEMORY_SCOPE_AGENT);
}
__device__ __forceinline__ void astore_rel(u32* p, u32 v) {
    __hip_atomic_store(p, v, __ATOMIC_RELEASE, __HIP_MEMORY_SCOPE_AGENT);
}

// stage gate-rows m=0,1 (rows 0..255) of a 512x128 f32 matrix -> LDS f16 pairs
__device__ __forceinline__ void stage_w2(const float* __restrict__ W,
                                         u32* __restrict__ wl, int t0) {
    const float2* src2 = (const float2*)W;
    for (int idx = t0; idx < 256 * 64; idx += 512) {
        const int row = idx >> 6, d = idx & 63;
        float2 v = src2[(size_t)row * 64 + d];
        h2 x; x.x = (f16)v.x; x.y = (f16)v.y;
        wl[(size_t)row * WRS + d] = __builtin_bit_cast(u32, x);
    }
}

// gates m=2,3 weight slice -> registers (32 dwords), pinned once (R14 as-is).
__device__ __forceinline__ void load_w_m23(const float* __restrict__ W,
                                           int rg, int kg, u32 (&w)[32]) {
    #pragma unroll
    for (int mh = 0; mh < 2; ++mh) {
        const float2* a =
            (const float2*)(W + (size_t)(rg + 128 * (2 + mh)) * HID + kg * 32);
        #pragma unroll
        for (int i = 0; i < 16; ++i) {
            float2 v = a[i];
            h2 x; x.x = (f16)v.x; x.y = (f16)v.y;
            w[mh * 16 + i] = __builtin_bit_cast(u32, x);
        }
    }
    #pragma unroll
    for (int i = 0; i < 32; ++i) asm volatile("" : "+v"(w[i]));
}

// One step's 4-gate dot for thread (rg,kg)  (R14/R16 as-is).
__device__ __forceinline__ void dot_split(const u32* __restrict__ wl,
                                          int rg, int kg,
                                          const u32* __restrict__ hsl,
                                          const u32 (&wr)[32],
                                          float (&p)[4]) {
    uint4 hq[4];
    #pragma unroll
    for (int i4 = 0; i4 < 4; ++i4) hq[i4] = *(const uint4*)&hsl[i4 * 4];

    // LDS gates m = 0,1
    #pragma unroll
    for (int m = 0; m < 2; ++m) {
        const u32* wb = wl + (size_t)(rg + 128 * m) * WRS + kg * 16;
        #pragma unroll
        for (int i4 = 0; i4 < 4; ++i4) {
            const uint4 wv = *(const uint4*)&wb[i4 * 4];
            const u32* hw = (const u32*)&hq[i4];
            p[m] = DOT2U(wv.x, __builtin_bit_cast(h2, hw[0]), p[m]);
            p[m] = DOT2U(wv.y, __builtin_bit_cast(h2, hw[1]), p[m]);
            p[m] = DOT2U(wv.z, __builtin_bit_cast(h2, hw[2]), p[m]);
            p[m] = DOT2U(wv.w, __builtin_bit_cast(h2, hw[3]), p[m]);
        }
    }
    // register gates m = 2,3
    #pragma unroll
    for (int mh = 0; mh < 2; ++mh) {
        #pragma unroll
        for (int i4 = 0; i4 < 4; ++i4) {
            const u32* hw = (const u32*)&hq[i4];
            #pragma unroll
            for (int j = 0; j < 4; ++j)
                p[2 + mh] = DOT2U(wr[mh * 16 + i4 * 4 + j],
                                  __builtin_bit_cast(h2, hw[j]), p[2 + mh]);
        }
    }
}

// ============================================================================
// Kernel 1: XG0[b,t,j] = Wih0[row_j]·x[b,t] + bih0[row_j] + bhh0[row_j], f16.
// ============================================================================
__global__ __launch_bounds__(512) void xg_precompute(
    const float* __restrict__ X, const float* __restrict__ Wih0,
    const float* __restrict__ bih0, const float* __restrict__ bhh0,
    f16* __restrict__ XG)
{
    __shared__ float xs[16][DIN];
    const int blk = blockIdx.x;               // over B * (T/16)
    const int b   = blk / (TLEN / 16);
    const int tc  = blk % (TLEN / 16);
    const int j   = threadIdx.x;
    const int row = (j >> 2) + 128 * (j & 3);

    const float* xsrc = X + ((size_t)b * TLEN + (size_t)tc * 16) * DIN;
    for (int i = j; i < 16 * DIN; i += 512) ((float*)xs)[i] = xsrc[i];
    __syncthreads();

    f4 w[16];
    const f4* wp = (const f4*)(Wih0 + (size_t)row * DIN);
    #pragma unroll
    for (int i = 0; i < 16; ++i) w[i] = wp[i];
    const float bias = bih0[row] + bhh0[row];

    f16* dst = XG + ((size_t)b * TLEN + (size_t)tc * 16) * 512 + j;
    #pragma unroll 4
    for (int t = 0; t < 16; ++t) {
        float acc = bias;
        const f4* xv = (const f4*)&xs[t][0];
        #pragma unroll
        for (int i = 0; i < 16; ++i) {
            f4 x4 = xv[i];
            acc += w[i][0] * x4[0] + w[i][1] * x4[1] + w[i][2] * x4[2] + w[i][3] * x4[3];
        }
        dst[(size_t)t * 512] = (f16)acc;
    }
}

// ============================================================================
// Kernel 2: 3-stage pipeline (R14 structure; DPP qreduce). PROVEN at 2096 us.
// grid = 96: role = bid/32, batch = bid%32. Thread: rg = t0>>2, kg = t0&3.
// ============================================================================
__global__ __launch_bounds__(512, 1) void lstm2_pipe(
    const f16* __restrict__ XG0,
    const float* __restrict__ Whh0,
    const float* __restrict__ Wih1, const float* __restrict__ Whh1,
    const float* __restrict__ bih1, const float* __restrict__ bhh1,
    float* __restrict__ Out,
    u32* __restrict__ H0g,     // [BATCH][TLEN][64] u32 (f16 pairs)
    u32* __restrict__ XG1,     // [BATCH][RING][512] u32 (f32 bits)
    u32* __restrict__ Flags)   // 96 slots x 16 u32
{
    __shared__ alignas(16) u32 pool[21632];

    const int role = blockIdx.x / BATCH;
    const int b    = blockIdx.x % BATCH;
    const int t0   = threadIdx.x;
    const int rg   = t0 >> 2;
    const int kg   = t0 & 3;

    u32* F0 = Flags + (size_t)b * 16;
    u32* F1 = Flags + (size_t)(32 + b) * 16;
    u32* C2 = Flags + (size_t)(64 + b) * 16;

    if (role == 0) {
        // ---------------- layer-0 cell ----------------
        stage_w2(Whh0, pool, t0);
        u32 wr[32];
        load_w_m23(Whh0, rg, kg, wr);
        u32* hl = pool + 17408;               // [2][64] dwords (f16 pairs)
        if (t0 < 128) hl[t0] = 0u;
        float c0 = 0.0f;
        const f16* xgp = XG0 + (size_t)b * TLEN * 512 + t0;
        u32* h0out = H0g + (size_t)b * TLEN * 64;
        f16 xga = xgp[0];
        f16 xgb = xgp[512];
        __syncthreads();

        for (int t = 0; t < TLEN; ++t) {
            const int cur = t & 1, prv = cur ^ 1;
            const float xgv = (float)xga;
            xga = xgb;
            { int tn = (t + 2 < TLEN) ? t + 2 : TLEN - 1; xgb = xgp[(size_t)tn * 512]; }

            float p[4];
            #pragma unroll
            for (int m = 0; m < 4; ++m) p[m] = (kg == m) ? xgv : 0.0f;
            dot_split(pool, rg, kg, hl + prv * 64 + kg * 16, wr, p);
            qreduce(p);
            float ii = sigm(p[0]), ff = sigm(p[1]);
            float gg = tanh_c(p[2]), oo = sigm(p[3]);
            c0 = ff * c0 + ii * gg;
            if (kg == 0) {
                f16* hf = (f16*)(hl + cur * 64);
                hf[rg] = (f16)(oo * tanh_c(c0));
            }
            __syncthreads();
            if (t0 < 64)
                astore_rlx(&h0out[(size_t)t * 64 + t0], hl[cur * 64 + t0]);
            if (t0 == 0 && (t & (CHK - 1)) == (CHK - 1))
                astore_rel(F0, (u32)(t + 1));
        }
    } else if (role == 1) {
        // ---------------- xg1 producer, chunk-prefetched ----------------
        stage_w2(Wih1, pool, t0);
        u32 wr[32];
        load_w_m23(Wih1, rg, kg, wr);
        u32* h0c = pool + 17408;              // [CHK*64] dwords
        const int rowk = rg + 128 * kg;
        const float B1 = bih1[rowk] + bhh1[rowk];
        u32* H0in = H0g + (size_t)b * TLEN * 64;
        u32* xout = XG1 + (size_t)b * RING * 512;
        u32 sc = 0;
        __syncthreads();

        for (int c = 0; c < TLEN / CHK; ++c) {
            const int tbase = c * CHK;
            if (t0 == 0) {
                u32 av; long g = 0;
                do { av = aload_acq(F0);
                     if (av >= (u32)(tbase + CHK)) break;
                     __builtin_amdgcn_s_sleep(2);
                } while (++g < 50000000L);
                if (tbase + CHK > (int)sc + (RING - 64)) {     // backpressure
                    g = 0;
                    do { sc = aload_rlx(C2);
                         if (tbase + CHK <= (int)sc + (RING - 64)) break;
                         __builtin_amdgcn_s_sleep(2);
                    } while (++g < 50000000L);
                }
            }
            __syncthreads();                        // poll done; h0c reusable
            h0c[t0] = aload_rlx(&H0in[(size_t)tbase * 64 + t0]);  // 512 = CHK*64
            __syncthreads();

            #pragma unroll
            for (int s = 0; s < CHK; ++s) {
                const int t = tbase + s;
                float p[4];
                #pragma unroll
                for (int m = 0; m < 4; ++m) p[m] = (kg == m) ? B1 : 0.0f;
                dot_split(pool, rg, kg, h0c + s * 64 + kg * 16, wr, p);
                qreduce(p);
                astore_rlx(&xout[(size_t)(t & (RING - 1)) * 512 + t0],
                           __builtin_bit_cast(u32, p[kg]));
            }
            asm volatile("s_waitcnt vmcnt(0)" ::: "memory");
            __syncthreads();
            if (t0 == 0) astore_rel(F1, (u32)(tbase + CHK));
        }
    } else {
        // ---------------- layer-1 cell, chunk-prefetched ----------------
        stage_w2(Whh1, pool, t0);
        u32 wr[32];
        load_w_m23(Whh1, rg, kg, wr);
        u32* xgc = pool + 17408;              // [CHK*512] dwords
        u32* hl  = pool + 21504;              // [2][64] dwords
        if (t0 < 128) hl[t0] = 0u;
        u32* xin = XG1 + (size_t)b * RING * 512;
        float c1 = 0.0f;
        __syncthreads();

        for (int c = 0; c < TLEN / CHK; ++c) {
            const int tbase = c * CHK;
            if (t0 == 0) {
                u32 av; long g = 0;
                do { av = aload_acq(F1);
                     if (av >= (u32)(tbase + CHK)) break;
                     __builtin_amdgcn_s_sleep(2);
                } while (++g < 50000000L);
            }
            __syncthreads();
            const size_t rbase = (size_t)(tbase & (RING - 1)) * 512;
            #pragma unroll
            for (int k = 0; k < CHK; ++k)
                xgc[k * 512 + t0] = aload_rlx(&xin[rbase + k * 512 + t0]);
            __syncthreads();

            #pragma unroll 1
            for (int s = 0; s < CHK; ++s) {
                const int t = tbase + s;
                const int cur = t & 1, prv = cur ^ 1;
                const float xgv = __builtin_bit_cast(float, xgc[s * 512 + t0]);

                float q[4];
                #pragma unroll
                for (int m = 0; m < 4; ++m) q[m] = (kg == m) ? xgv : 0.0f;
                dot_split(pool, rg, kg, hl + prv * 64 + kg * 16, wr, q);
                qreduce(q);
                float ii = sigm(q[0]), ff = sigm(q[1]);
                float gg = tanh_c(q[2]), oo = sigm(q[3]);
                c1 = ff * c1 + ii * gg;
                float h1v = oo * tanh_c(c1);
                if (kg == 0) {
                    f16* hf = (f16*)(hl + cur * 64);
                    hf[rg] = (f16)h1v;
                    Out[((size_t)b * TLEN + t) * HID + rg] = h1v;
                }
                __syncthreads();
            }
            if (t0 == 0 && (c & 3) == 3)
                astore_rlx(C2, (u32)(tbase + CHK));
        }
    }
}

// ============================================================================
// Fallback (ws too small): round-1 kernel structure, known-correct (shfl).
// ============================================================================
__global__ __launch_bounds__(512, 2) void lstm2_persist(
    const float* __restrict__ X,
    const float* __restrict__ Wih0, const float* __restrict__ Whh0,
    const float* __restrict__ bih0, const float* __restrict__ bhh0,
    const float* __restrict__ Wih1, const float* __restrict__ Whh1,
    const float* __restrict__ bih1, const float* __restrict__ bhh1,
    float* __restrict__ Out)
{
    __shared__ unsigned int wih0_lds[512 * 33];
    __shared__ f16 h0buf[2][HID];
    __shared__ f16 h1buf[2][HID];

    const int b  = blockIdx.x;
    const int t  = threadIdx.x;
    const int rg = t >> 2;
    const int kg = t & 3;

    {
        const float2* src = (const float2*)(Wih0 + t * DIN);
        #pragma unroll
        for (int i = 0; i < 32; ++i) {
            float2 v = src[i];
            h2 p; p.x = (f16)v.x; p.y = (f16)v.y;
            wih0_lds[t * 33 + i] = __builtin_bit_cast(unsigned int, p);
        }
    }
    if (t < HID) {
        h0buf[0][t] = (f16)0.0f; h0buf[1][t] = (f16)0.0f;
        h1buf[0][t] = (f16)0.0f; h1buf[1][t] = (f16)0.0f;
    }

    h2 whh0[4][16], wih1[4][16], whh1[4][16];
    float bi0[4], bi1[4];
    #pragma unroll
    for (int m = 0; m < 4; ++m) {
        const int row = rg + 128 * m;
        const float2* a = (const float2*)(Whh0 + row * HID + kg * 32);
        const float2* c = (const float2*)(Wih1 + row * HID + kg * 32);
        const float2* d = (const float2*)(Whh1 + row * HID + kg * 32);
        #pragma unroll
        for (int i = 0; i < 16; ++i) {
            float2 v; h2 w;
            v = a[i]; w.x = (f16)v.x; w.y = (f16)v.y; whh0[m][i] = w;
            v = c[i]; w.x = (f16)v.x; w.y = (f16)v.y; wih1[m][i] = w;
            v = d[i]; w.x = (f16)v.x; w.y = (f16)v.y; whh1[m][i] = w;
        }
        bi0[m] = (kg == 0) ? (bih0[row] + bhh0[row]) : 0.0f;
        bi1[m] = (kg == 0) ? (bih1[row] + bhh1[row]) : 0.0f;
    }

    float c0 = 0.0f, c1 = 0.0f;
    __syncthreads();

    f4 xA[4], xB[4];
    {
        const f4* xp = (const f4*)(X + ((size_t)b * TLEN) * DIN + kg * 16);
        #pragma unroll
        for (int j = 0; j < 4; ++j) xA[j] = xp[j];
    }

    auto step = [&](int tt, f4 (&xc)[4], f4 (&xn)[4]) {
        const int cur = tt & 1, nxt = cur ^ 1;
        h2 xh[8];
        const float* xf = (const float*)xc;
        #pragma unroll
        for (int j = 0; j < 8; ++j) {
            h2 p; p.x = (f16)xf[2 * j]; p.y = (f16)xf[2 * j + 1];
            xh[j] = p;
        }
        {
            const int tn = (tt + 1 < TLEN) ? tt + 1 : TLEN - 1;
            const f4* xp = (const f4*)(X + ((size_t)b * TLEN + tn) * DIN + kg * 16);
            #pragma unroll
            for (int j = 0; j < 4; ++j) xn[j] = xp[j];
        }
        float p0[4];
        #pragma unroll
        for (int m = 0; m < 4; ++m) p0[m] = bi0[m];
        #pragma unroll
        for (int m = 0; m < 4; ++m) {
            const unsigned int* wr = &wih0_lds[(rg + 128 * m) * 33 + kg * 8];
            #pragma unroll
            for (int i = 0; i < 8; ++i) {
                h2 w = __builtin_bit_cast(h2, wr[i]);
                p0[m] = FDOT2(w, xh[i], p0[m]);
            }
        }
        {
            const unsigned int* hr = (const unsigned int*)&h0buf[cur][0];
            #pragma unroll
            for (int i = 0; i < 16; ++i) {
                h2 hv = __builtin_bit_cast(h2, hr[kg * 16 + i]);
                #pragma unroll
                for (int m = 0; m < 4; ++m)
                    p0[m] = FDOT2(whh0[m][i], hv, p0[m]);
            }
        }
        #pragma unroll
        for (int m = 0; m < 4; ++m) {
            p0[m] += __shfl_xor(p0[m], 1, 4);
            p0[m] += __shfl_xor(p0[m], 2, 4);
        }
        {
            float ii = sigm(p0[0]), ff = sigm(p0[1]);
            float gg = tanh_c(p0[2]), oo = sigm(p0[3]);
            c0 = ff * c0 + ii * gg;
            float h0v = oo * tanh_c(c0);
            if (kg == 0) h0buf[nxt][rg] = (f16)h0v;
        }
        __syncthreads();
        float q[4];
        #pragma unroll
        for (int m = 0; m < 4; ++m) q[m] = bi1[m];
        {
            const unsigned int* hr = (const unsigned int*)&h0buf[nxt][0];
            #pragma unroll
            for (int i = 0; i < 16; ++i) {
                h2 hv = __builtin_bit_cast(h2, hr[kg * 16 + i]);
                #pragma unroll
                for (int m = 0; m < 4; ++m)
                    q[m] = FDOT2(wih1[m][i], hv, q[m]);
            }
        }
        {
            const unsigned int* hr = (const unsigned int*)&h1buf[cur][0];
            #pragma unroll
            for (int i = 0; i < 16; ++i) {
                h2 hv = __builtin_bit_cast(h2, hr[kg * 16 + i]);
                #pragma unroll
                for (int m = 0; m < 4; ++m)
                    q[m] = FDOT2(whh1[m][i], hv, q[m]);
            }
        }
        #pragma unroll
        for (int m = 0; m < 4; ++m) {
            q[m] += __shfl_xor(q[m], 1, 4);
            q[m] += __shfl_xor(q[m], 2, 4);
        }
        {
            float ii = sigm(q[0]), ff = sigm(q[1]);
            float gg = tanh_c(q[2]), oo = sigm(q[3]);
            c1 = ff * c1 + ii * gg;
            float h1v = oo * tanh_c(c1);
            if (kg == 0) {
                h1buf[nxt][rg] = (f16)h1v;
                Out[((size_t)b * TLEN + tt) * HID + rg] = h1v;
            }
        }
        __syncthreads();
    };

    for (int tt = 0; tt < TLEN; tt += 2) {
        step(tt, xA, xB);
        step(tt + 1, xB, xA);
    }
}

extern "C" void kernel_launch(void* const* d_in, const int* in_sizes, int n_in,
                              void* d_out, int out_size, void* d_ws, size_t ws_size,
                              hipStream_t stream) {
    const float* X    = (const float*)d_in[0];
    const float* Wih0 = (const float*)d_in[1];
    const float* Whh0 = (const float*)d_in[2];
    const float* bih0 = (const float*)d_in[3];
    const float* bhh0 = (const float*)d_in[4];
    const float* Wih1 = (const float*)d_in[5];
    const float* Whh1 = (const float*)d_in[6];
    const float* bih1 = (const float*)d_in[7];
    const float* bhh1 = (const float*)d_in[8];
    float* Out = (float*)d_out;

    const size_t XG0_B  = (size_t)BATCH * TLEN * 512 * 2;   // 64 MiB f16
    const size_t H0_B   = (size_t)BATCH * TLEN * 64 * 4;    // 16 MiB
    const size_t XG1_B  = (size_t)BATCH * RING * 512 * 4;   // 16 MiB
    const size_t FLAG_B = 96 * 16 * 4;
    const size_t NEED   = XG0_B + H0_B + XG1_B + FLAG_B;

    if (ws_size >= NEED) {
        char* ws = (char*)d_ws;
        f16* XG0   = (f16*)ws;
        u32* H0g   = (u32*)(ws + XG0_B);
        u32* XG1   = (u32*)(ws + XG0_B + H0_B);
        u32* Flags = (u32*)(ws + XG0_B + H0_B + XG1_B);

        hipMemsetAsync(Flags, 0, FLAG_B, stream);   // re-arm sync every launch
        xg_precompute<<<dim3(BATCH * (TLEN / 16)), dim3(512), 0, stream>>>(
            X, Wih0, bih0, bhh0, XG0);
        lstm2_pipe<<<dim3(3 * BATCH), dim3(512), 0, stream>>>(
            XG0, Whh0, Wih1, Whh1, bih1, bhh1, Out, H0g, XG1, Flags);
    } else {
        lstm2_persist<<<dim3(BATCH), dim3(512), 0, stream>>>(
            X, Wih0, Whh0, bih0, bhh0, Wih1, Whh1, bih1, bhh1, Out);
    }
}

// Round 19
// 1997.571 us; speedup vs baseline: 1.6381x; 1.0481x over previous
//
#include <hip/hip_runtime.h>

#define TLEN 2048
#define BATCH 32
#define DIN 64
#define HID 128
#define RING 256   // xg1 ring depth (steps); power of 2, multiple of CHK
#define CHK 8      // pipeline chunk (steps)

typedef _Float16 f16;
typedef _Float16 h2 __attribute__((ext_vector_type(2)));
typedef float f4 __attribute__((ext_vector_type(4)));
typedef unsigned int u32;

#if defined(__has_builtin)
#if __has_builtin(__builtin_amdgcn_fdot2)
#define FDOT2(a, b, c) __builtin_amdgcn_fdot2((a), (b), (c), false)
#endif
#endif
#ifndef FDOT2
#define FDOT2(a, b, c) ((c) + (float)(a).x * (float)(b).x + (float)(a).y * (float)(b).y)
#endif
#define DOT2U(wu, hv, acc) FDOT2(__builtin_bit_cast(h2, (wu)), (hv), (acc))

// ---- fast activations (R12/R14-proven; absmax unchanged) ----
#if defined(__has_builtin)
#if __has_builtin(__builtin_amdgcn_exp2f)
#define FEXP2(x) __builtin_amdgcn_exp2f(x)
#endif
#if __has_builtin(__builtin_amdgcn_rcpf)
#define FRCP(x) __builtin_amdgcn_rcpf(x)
#endif
#endif
#ifndef FEXP2
#define FEXP2(x) __expf((x) * 0.69314718f)
#endif
#ifndef FRCP
#define FRCP(x) (1.0f / (x))
#endif

__device__ __forceinline__ float sigm(float x) {
    return FRCP(1.0f + FEXP2(-1.44269504f * x));
}
__device__ __forceinline__ float tanh_c(float x) {
    x = fminf(fmaxf(x, -15.0f), 15.0f);
    float e = FEXP2(2.88539008f * x);
    return (e - 1.0f) * FRCP(e + 1.0f);
}

// ---- quad butterfly via DPP quad_perm (R16-proven correct, VALU pipe) ----
__device__ __forceinline__ float qswap1_dpp(float v) {
    const int s = __builtin_bit_cast(int, v);
    return __builtin_bit_cast(float,
        __builtin_amdgcn_update_dpp(s, s, 0xB1, 0xF, 0xF, false));
}
__device__ __forceinline__ float qswap2_dpp(float v) {
    const int s = __builtin_bit_cast(int, v);
    return __builtin_bit_cast(float,
        __builtin_amdgcn_update_dpp(s, s, 0x4E, 0xF, 0xF, false));
}
__device__ __forceinline__ void qreduce(float (&v)[4]) {
    #pragma unroll
    for (int m = 0; m < 4; ++m) {
        v[m] += qswap1_dpp(v[m]);
        v[m] += qswap2_dpp(v[m]);
    }
}

// agent-scope atomics (R8/R9-proven cross-XCD path)
__device__ __forceinline__ u32 aload_rlx(const u32* p) {
    return __hip_atomic_load(p, __ATOMIC_RELAXED, __HIP_MEMORY_SCOPE_AGENT);
}
__device__ __forceinline__ u32 aload_acq(const u32* p) {
    return __hip_atomic_load(p, __ATOMIC_ACQUIRE, __HIP_MEMORY_SCOPE_AGENT);
}
__device__ __forceinline__ void astore_rlx(u32* p, u32 v) {
    __hip_atomic_store(p, v, __ATOMIC_RELAXED, __HIP_MEMORY_SCOPE_AGENT);
}
__device__ __forceinline__ void astore_rel(u32* p, u32 v) {
    __hip_atomic_store(p, v, __ATOMIC_RELEASE, __HIP_MEMORY_SCOPE_AGENT);
}

// ALL 4 gates' weight slices -> AGPRs (64 dwords f16 pairs), pinned ONCE.
// AGPR residency is the one register path HW-proven on this toolchain
// (R11/R15: "+a" one-time pins held 192+ dwords across the whole loop,
// FETCH=13MB => no reloads). R7's regression was in-loop RE-pins; avoided.
__device__ __forceinline__ void load_w_all(const float* __restrict__ W,
                                           int rg, int kg, u32 (&w)[64]) {
    #pragma unroll
    for (int m = 0; m < 4; ++m) {
        const float2* a =
            (const float2*)(W + (size_t)(rg + 128 * m) * HID + kg * 32);
        #pragma unroll
        for (int i = 0; i < 16; ++i) {
            float2 v = a[i];
            h2 x; x.x = (f16)v.x; x.y = (f16)v.y;
            w[m * 16 + i] = __builtin_bit_cast(u32, x);
        }
    }
    #pragma unroll
    for (int i = 0; i < 64; ++i) asm volatile("" : "+a"(w[i]));
}

// One step's 4-gate dot for thread (rg,kg): weights from AGPRs, h from LDS.
// Per-gate accumulation order identical to R12/R14/R16 -> bit-identical out.
__device__ __forceinline__ void dot_all(const u32 (&wr)[64],
                                        const u32* __restrict__ hsl,
                                        float (&p)[4]) {
    uint4 hq[4];
    #pragma unroll
    for (int i4 = 0; i4 < 4; ++i4) hq[i4] = *(const uint4*)&hsl[i4 * 4];

    #pragma unroll
    for (int m = 0; m < 4; ++m) {
        #pragma unroll
        for (int i4 = 0; i4 < 4; ++i4) {
            const u32* hw = (const u32*)&hq[i4];
            #pragma unroll
            for (int j = 0; j < 4; ++j)
                p[m] = DOT2U(wr[m * 16 + i4 * 4 + j],
                             __builtin_bit_cast(h2, hw[j]), p[m]);
        }
    }
}

// ============================================================================
// Kernel 1: XG0[b,t,j] = Wih0[row_j]·x[b,t] + bih0[row_j] + bhh0[row_j], f16.
// ============================================================================
__global__ __launch_bounds__(512) void xg_precompute(
    const float* __restrict__ X, const float* __restrict__ Wih0,
    const float* __restrict__ bih0, const float* __restrict__ bhh0,
    f16* __restrict__ XG)
{
    __shared__ float xs[16][DIN];
    const int blk = blockIdx.x;               // over B * (T/16)
    const int b   = blk / (TLEN / 16);
    const int tc  = blk % (TLEN / 16);
    const int j   = threadIdx.x;
    const int row = (j >> 2) + 128 * (j & 3);

    const float* xsrc = X + ((size_t)b * TLEN + (size_t)tc * 16) * DIN;
    for (int i = j; i < 16 * DIN; i += 512) ((float*)xs)[i] = xsrc[i];
    __syncthreads();

    f4 w[16];
    const f4* wp = (const f4*)(Wih0 + (size_t)row * DIN);
    #pragma unroll
    for (int i = 0; i < 16; ++i) w[i] = wp[i];
    const float bias = bih0[row] + bhh0[row];

    f16* dst = XG + ((size_t)b * TLEN + (size_t)tc * 16) * 512 + j;
    #pragma unroll 4
    for (int t = 0; t < 16; ++t) {
        float acc = bias;
        const f4* xv = (const f4*)&xs[t][0];
        #pragma unroll
        for (int i = 0; i < 16; ++i) {
            f4 x4 = xv[i];
            acc += w[i][0] * x4[0] + w[i][1] * x4[1] + w[i][2] * x4[2] + w[i][3] * x4[3];
        }
        dst[(size_t)t * 512] = (f16)acc;
    }
}

// ============================================================================
// Kernel 2: 3-stage pipeline (R16 protocol), ALL weights AGPR-resident.
// Weight LDS eliminated: per-step LDS traffic = 4 h-b128 reads only.
// grid = 96: role = bid/32, batch = bid%32. Thread: rg = t0>>2, kg = t0&3.
// ============================================================================
__global__ __launch_bounds__(512, 1) void lstm2_pipe(
    const f16* __restrict__ XG0,
    const float* __restrict__ Whh0,
    const float* __restrict__ Wih1, const float* __restrict__ Whh1,
    const float* __restrict__ bih1, const float* __restrict__ bhh1,
    float* __restrict__ Out,
    u32* __restrict__ H0g,     // [BATCH][TLEN][64] u32 (f16 pairs)
    u32* __restrict__ XG1,     // [BATCH][RING][512] u32 (f32 bits)
    u32* __restrict__ Flags)   // 96 slots x 16 u32
{
    // role0: hl 128dw @0 | role1: h0c 512dw @0 | role2: xgc 4096dw @0, hl @4096
    __shared__ alignas(16) u32 pool[4224];

    const int role = blockIdx.x / BATCH;
    const int b    = blockIdx.x % BATCH;
    const int t0   = threadIdx.x;
    const int rg   = t0 >> 2;
    const int kg   = t0 & 3;

    u32* F0 = Flags + (size_t)b * 16;
    u32* F1 = Flags + (size_t)(32 + b) * 16;
    u32* C2 = Flags + (size_t)(64 + b) * 16;

    if (role == 0) {
        // ---------------- layer-0 cell ----------------
        u32 wr[64];
        load_w_all(Whh0, rg, kg, wr);
        u32* hl = pool;                       // [2][64] dwords (f16 pairs)
        if (t0 < 128) hl[t0] = 0u;
        float c0 = 0.0f;
        const f16* xgp = XG0 + (size_t)b * TLEN * 512 + t0;
        u32* h0out = H0g + (size_t)b * TLEN * 64;
        f16 xga = xgp[0];
        f16 xgb = xgp[512];
        __syncthreads();

        for (int t = 0; t < TLEN; ++t) {
            const int cur = t & 1, prv = cur ^ 1;
            const float xgv = (float)xga;
            xga = xgb;
            { int tn = (t + 2 < TLEN) ? t + 2 : TLEN - 1; xgb = xgp[(size_t)tn * 512]; }

            float p[4];
            #pragma unroll
            for (int m = 0; m < 4; ++m) p[m] = (kg == m) ? xgv : 0.0f;
            dot_all(wr, hl + prv * 64 + kg * 16, p);
            qreduce(p);
            float ii = sigm(p[0]), ff = sigm(p[1]);
            float gg = tanh_c(p[2]), oo = sigm(p[3]);
            c0 = ff * c0 + ii * gg;
            if (kg == 0) {
                f16* hf = (f16*)(hl + cur * 64);
                hf[rg] = (f16)(oo * tanh_c(c0));
            }
            __syncthreads();
            if (t0 < 64)
                astore_rlx(&h0out[(size_t)t * 64 + t0], hl[cur * 64 + t0]);
            if (t0 == 0 && (t & (CHK - 1)) == (CHK - 1))
                astore_rel(F0, (u32)(t + 1));
        }
    } else if (role == 1) {
        // ---------------- xg1 producer, chunk-prefetched ----------------
        u32 wr[64];
        load_w_all(Wih1, rg, kg, wr);
        u32* h0c = pool;                      // [CHK*64] dwords
        const int rowk = rg + 128 * kg;
        const float B1 = bih1[rowk] + bhh1[rowk];
        u32* H0in = H0g + (size_t)b * TLEN * 64;
        u32* xout = XG1 + (size_t)b * RING * 512;
        u32 sc = 0;
        __syncthreads();

        for (int c = 0; c < TLEN / CHK; ++c) {
            const int tbase = c * CHK;
            if (t0 == 0) {
                u32 av; long g = 0;
                do { av = aload_acq(F0);
                     if (av >= (u32)(tbase + CHK)) break;
                     __builtin_amdgcn_s_sleep(2);
                } while (++g < 50000000L);
                if (tbase + CHK > (int)sc + (RING - 64)) {     // backpressure
                    g = 0;
                    do { sc = aload_rlx(C2);
                         if (tbase + CHK <= (int)sc + (RING - 64)) break;
                         __builtin_amdgcn_s_sleep(2);
                    } while (++g < 50000000L);
                }
            }
            __syncthreads();                        // poll done; h0c reusable
            h0c[t0] = aload_rlx(&H0in[(size_t)tbase * 64 + t0]);  // 512 = CHK*64
            __syncthreads();

            #pragma unroll
            for (int s = 0; s < CHK; ++s) {
                const int t = tbase + s;
                float p[4];
                #pragma unroll
                for (int m = 0; m < 4; ++m) p[m] = (kg == m) ? B1 : 0.0f;
                dot_all(wr, h0c + s * 64 + kg * 16, p);
                qreduce(p);
                astore_rlx(&xout[(size_t)(t & (RING - 1)) * 512 + t0],
                           __builtin_bit_cast(u32, p[kg]));
            }
            asm volatile("s_waitcnt vmcnt(0)" ::: "memory");
            __syncthreads();
            if (t0 == 0) astore_rel(F1, (u32)(tbase + CHK));
        }
    } else {
        // ---------------- layer-1 cell, chunk-prefetched ----------------
        u32 wr[64];
        load_w_all(Whh1, rg, kg, wr);
        u32* xgc = pool;                      // [CHK*512] dwords
        u32* hl  = pool + 4096;               // [2][64] dwords
        if (t0 < 128) hl[t0] = 0u;
        u32* xin = XG1 + (size_t)b * RING * 512;
        float c1 = 0.0f;
        __syncthreads();

        for (int c = 0; c < TLEN / CHK; ++c) {
            const int tbase = c * CHK;
            if (t0 == 0) {
                u32 av; long g = 0;
                do { av = aload_acq(F1);
                     if (av >= (u32)(tbase + CHK)) break;
                     __builtin_amdgcn_s_sleep(2);
                } while (++g < 50000000L);
            }
            __syncthreads();
            const size_t rbase = (size_t)(tbase & (RING - 1)) * 512;
            #pragma unroll
            for (int k = 0; k < CHK; ++k)
                xgc[k * 512 + t0] = aload_rlx(&xin[rbase + k * 512 + t0]);
            __syncthreads();

            #pragma unroll 1
            for (int s = 0; s < CHK; ++s) {
                const int t = tbase + s;
                const int cur = t & 1, prv = cur ^ 1;
                const float xgv = __builtin_bit_cast(float, xgc[s * 512 + t0]);

                float q[4];
                #pragma unroll
                for (int m = 0; m < 4; ++m) q[m] = (kg == m) ? xgv : 0.0f;
                dot_all(wr, hl + prv * 64 + kg * 16, q);
                qreduce(q);
                float ii = sigm(q[0]), ff = sigm(q[1]);
                float gg = tanh_c(q[2]), oo = sigm(q[3]);
                c1 = ff * c1 + ii * gg;
                float h1v = oo * tanh_c(c1);
                if (kg == 0) {
                    f16* hf = (f16*)(hl + cur * 64);
                    hf[rg] = (f16)h1v;
                    Out[((size_t)b * TLEN + t) * HID + rg] = h1v;
                }
                __syncthreads();
            }
            if (t0 == 0 && (c & 3) == 3)
                astore_rlx(C2, (u32)(tbase + CHK));
        }
    }
}

// ============================================================================
// Fallback (ws too small): round-1 kernel structure, known-correct (shfl).
// ============================================================================
__global__ __launch_bounds__(512, 2) void lstm2_persist(
    const float* __restrict__ X,
    const float* __restrict__ Wih0, const float* __restrict__ Whh0,
    const float* __restrict__ bih0, const float* __restrict__ bhh0,
    const float* __restrict__ Wih1, const float* __restrict__ Whh1,
    const float* __restrict__ bih1, const float* __restrict__ bhh1,
    float* __restrict__ Out)
{
    __shared__ unsigned int wih0_lds[512 * 33];
    __shared__ f16 h0buf[2][HID];
    __shared__ f16 h1buf[2][HID];

    const int b  = blockIdx.x;
    const int t  = threadIdx.x;
    const int rg = t >> 2;
    const int kg = t & 3;

    {
        const float2* src = (const float2*)(Wih0 + t * DIN);
        #pragma unroll
        for (int i = 0; i < 32; ++i) {
            float2 v = src[i];
            h2 p; p.x = (f16)v.x; p.y = (f16)v.y;
            wih0_lds[t * 33 + i] = __builtin_bit_cast(unsigned int, p);
        }
    }
    if (t < HID) {
        h0buf[0][t] = (f16)0.0f; h0buf[1][t] = (f16)0.0f;
        h1buf[0][t] = (f16)0.0f; h1buf[1][t] = (f16)0.0f;
    }

    h2 whh0[4][16], wih1[4][16], whh1[4][16];
    float bi0[4], bi1[4];
    #pragma unroll
    for (int m = 0; m < 4; ++m) {
        const int row = rg + 128 * m;
        const float2* a = (const float2*)(Whh0 + row * HID + kg * 32);
        const float2* c = (const float2*)(Wih1 + row * HID + kg * 32);
        const float2* d = (const float2*)(Whh1 + row * HID + kg * 32);
        #pragma unroll
        for (int i = 0; i < 16; ++i) {
            float2 v; h2 w;
            v = a[i]; w.x = (f16)v.x; w.y = (f16)v.y; whh0[m][i] = w;
            v = c[i]; w.x = (f16)v.x; w.y = (f16)v.y; wih1[m][i] = w;
            v = d[i]; w.x = (f16)v.x; w.y = (f16)v.y; whh1[m][i] = w;
        }
        bi0[m] = (kg == 0) ? (bih0[row] + bhh0[row]) : 0.0f;
        bi1[m] = (kg == 0) ? (bih1[row] + bhh1[row]) : 0.0f;
    }

    float c0 = 0.0f, c1 = 0.0f;
    __syncthreads();

    f4 xA[4], xB[4];
    {
        const f4* xp = (const f4*)(X + ((size_t)b * TLEN) * DIN + kg * 16);
        #pragma unroll
        for (int j = 0; j < 4; ++j) xA[j] = xp[j];
    }

    auto step = [&](int tt, f4 (&xc)[4], f4 (&xn)[4]) {
        const int cur = tt & 1, nxt = cur ^ 1;
        h2 xh[8];
        const float* xf = (const float*)xc;
        #pragma unroll
        for (int j = 0; j < 8; ++j) {
            h2 p; p.x = (f16)xf[2 * j]; p.y = (f16)xf[2 * j + 1];
            xh[j] = p;
        }
        {
            const int tn = (tt + 1 < TLEN) ? tt + 1 : TLEN - 1;
            const f4* xp = (const f4*)(X + ((size_t)b * TLEN + tn) * DIN + kg * 16);
            #pragma unroll
            for (int j = 0; j < 4; ++j) xn[j] = xp[j];
        }
        float p0[4];
        #pragma unroll
        for (int m = 0; m < 4; ++m) p0[m] = bi0[m];
        #pragma unroll
        for (int m = 0; m < 4; ++m) {
            const unsigned int* wr = &wih0_lds[(rg + 128 * m) * 33 + kg * 8];
            #pragma unroll
            for (int i = 0; i < 8; ++i) {
                h2 w = __builtin_bit_cast(h2, wr[i]);
                p0[m] = FDOT2(w, xh[i], p0[m]);
            }
        }
        {
            const unsigned int* hr = (const unsigned int*)&h0buf[cur][0];
            #pragma unroll
            for (int i = 0; i < 16; ++i) {
                h2 hv = __builtin_bit_cast(h2, hr[kg * 16 + i]);
                #pragma unroll
                for (int m = 0; m < 4; ++m)
                    p0[m] = FDOT2(whh0[m][i], hv, p0[m]);
            }
        }
        #pragma unroll
        for (int m = 0; m < 4; ++m) {
            p0[m] += __shfl_xor(p0[m], 1, 4);
            p0[m] += __shfl_xor(p0[m], 2, 4);
        }
        {
            float ii = sigm(p0[0]), ff = sigm(p0[1]);
            float gg = tanh_c(p0[2]), oo = sigm(p0[3]);
            c0 = ff * c0 + ii * gg;
            float h0v = oo * tanh_c(c0);
            if (kg == 0) h0buf[nxt][rg] = (f16)h0v;
        }
        __syncthreads();
        float q[4];
        #pragma unroll
        for (int m = 0; m < 4; ++m) q[m] = bi1[m];
        {
            const unsigned int* hr = (const unsigned int*)&h0buf[nxt][0];
            #pragma unroll
            for (int i = 0; i < 16; ++i) {
                h2 hv = __builtin_bit_cast(h2, hr[kg * 16 + i]);
                #pragma unroll
                for (int m = 0; m < 4; ++m)
                    q[m] = FDOT2(wih1[m][i], hv, q[m]);
            }
        }
        {
            const unsigned int* hr = (const unsigned int*)&h1buf[cur][0];
            #pragma unroll
            for (int i = 0; i < 16; ++i) {
                h2 hv = __builtin_bit_cast(h2, hr[kg * 16 + i]);
                #pragma unroll
                for (int m = 0; m < 4; ++m)
                    q[m] = FDOT2(whh1[m][i], hv, q[m]);
            }
        }
        #pragma unroll
        for (int m = 0; m < 4; ++m) {
            q[m] += __shfl_xor(q[m], 1, 4);
            q[m] += __shfl_xor(q[m], 2, 4);
        }
        {
            float ii = sigm(q[0]), ff = sigm(q[1]);
            float gg = tanh_c(q[2]), oo = sigm(q[3]);
            c1 = ff * c1 + ii * gg;
            float h1v = oo * tanh_c(c1);
            if (kg == 0) {
                h1buf[nxt][rg] = (f16)h1v;
                Out[((size_t)b * TLEN + tt) * HID + rg] = h1v;
            }
        }
        __syncthreads();
    };

    for (int tt = 0; tt < TLEN; tt += 2) {
        step(tt, xA, xB);
        step(tt + 1, xB, xA);
    }
}

extern "C" void kernel_launch(void* const* d_in, const int* in_sizes, int n_in,
                              void* d_out, int out_size, void* d_ws, size_t ws_size,
                              hipStream_t stream) {
    const float* X    = (const float*)d_in[0];
    const float* Wih0 = (const float*)d_in[1];
    const float* Whh0 = (const float*)d_in[2];
    const float* bih0 = (const float*)d_in[3];
    const float* bhh0 = (const float*)d_in[4];
    const float* Wih1 = (const float*)d_in[5];
    const float* Whh1 = (const float*)d_in[6];
    const float* bih1 = (const float*)d_in[7];
    const float* bhh1 = (const float*)d_in[8];
    float* Out = (float*)d_out;

    const size_t XG0_B  = (size_t)BATCH * TLEN * 512 * 2;   // 64 MiB f16
    const size_t H0_B   = (size_t)BATCH * TLEN * 64 * 4;    // 16 MiB
    const size_t XG1_B  = (size_t)BATCH * RING * 512 * 4;   // 16 MiB
    const size_t FLAG_B = 96 * 16 * 4;
    const size_t NEED   = XG0_B + H0_B + XG1_B + FLAG_B;

    if (ws_size >= NEED) {
        char* ws = (char*)d_ws;
        f16* XG0   = (f16*)ws;
        u32* H0g   = (u32*)(ws + XG0_B);
        u32* XG1   = (u32*)(ws + XG0_B + H0_B);
        u32* Flags = (u32*)(ws + XG0_B + H0_B + XG1_B);

        hipMemsetAsync(Flags, 0, FLAG_B, stream);   // re-arm sync every launch
        xg_precompute<<<dim3(BATCH * (TLEN / 16)), dim3(512), 0, stream>>>(
            X, Wih0, bih0, bhh0, XG0);
        lstm2_pipe<<<dim3(3 * BATCH), dim3(512), 0, stream>>>(
            XG0, Whh0, Wih1, Whh1, bih1, bhh1, Out, H0g, XG1, Flags);
    } else {
        lstm2_persist<<<dim3(BATCH), dim3(512), 0, stream>>>(
            X, Wih0, Whh0, bih0, bhh0, Wih1, Whh1, bih1, bhh1, Out);
    }
}